// Round 3
// baseline (109.702 us; speedup 1.0000x reference)
//
#include <hip/hip_runtime.h>

#define B_ 8
#define D_ 256
#define N_ 32768
#define F_ 256
#define K_ 16

// ws layout: e = ws[0 .. B*N)   (1 MB, exp(sims))
//            pp = ws + B*N, layout [3][B][64]  (per-chunk partial sums e, e^2, e^3)

__device__ __forceinline__ float sum4(float4 v) { return v.x + v.y + v.z + v.w; }

// ---------------------------------------------------------------------------
// K1: e[b][n] = exp(-(q . k_n)/16), plus per-chunk partials of e, e^2, e^3.
// 512 blocks (8 b x 64 chunks of 512 n) x 512 threads (2 blocks/CU).
// Thread (c,g): c = float4 column (128), g = d-quarter (4 x 64 d).
// ---------------------------------------------------------------------------
__global__ __launch_bounds__(512) void expsim_kernel(
    const float* __restrict__ q, const float* __restrict__ keys,
    float* __restrict__ e, float* __restrict__ pp) {
  const int b = blockIdx.x >> 6;
  const int chunk = blockIdx.x & 63;
  const int t = threadIdx.x;
  const int c = t & 127;
  const int g = t >> 7;
  __shared__ float qs[D_];
  __shared__ float4 part[3][128];
  __shared__ float pr[8][3];
  if (t < D_) qs[t] = q[b * D_ + t];
  __syncthreads();
  const int n0 = chunk * 512 + c * 4;
  const float* kp = keys + (size_t)b * D_ * N_ + (size_t)(g * 64) * N_ + n0;
  const float* qg = qs + g * 64;
  float ax = 0.f, ay = 0.f, az = 0.f, aw = 0.f;
#pragma unroll 8
  for (int d = 0; d < 64; ++d) {
    float4 kv = *reinterpret_cast<const float4*>(kp + (size_t)d * N_);
    float qd = qg[d];
    ax += qd * kv.x; ay += qd * kv.y; az += qd * kv.z; aw += qd * kv.w;
  }
  if (g > 0) part[g - 1][c] = make_float4(ax, ay, az, aw);
  __syncthreads();
  float s1 = 0.f, s2 = 0.f, s3 = 0.f;
  if (g == 0) {
    float4 p1 = part[0][c], p2 = part[1][c], p3 = part[2][c];
    float4 ev;
    ev.x = __expf(-0.0625f * (ax + p1.x + p2.x + p3.x));
    ev.y = __expf(-0.0625f * (ay + p1.y + p2.y + p3.y));
    ev.z = __expf(-0.0625f * (az + p1.z + p2.z + p3.z));
    ev.w = __expf(-0.0625f * (aw + p1.w + p2.w + p3.w));
    *reinterpret_cast<float4*>(e + (size_t)b * N_ + n0) = ev;
    float4 e2 = make_float4(ev.x * ev.x, ev.y * ev.y, ev.z * ev.z, ev.w * ev.w);
    s1 = sum4(ev);
    s2 = sum4(e2);
    s3 = e2.x * ev.x + e2.y * ev.y + e2.z * ev.z + e2.w * ev.w;
  }
  // all-thread reduce (waves 2..7 contribute zeros)
#pragma unroll
  for (int off = 32; off > 0; off >>= 1) {
    s1 += __shfl_xor(s1, off, 64);
    s2 += __shfl_xor(s2, off, 64);
    s3 += __shfl_xor(s3, off, 64);
  }
  if ((t & 63) == 0) { pr[t >> 6][0] = s1; pr[t >> 6][1] = s2; pr[t >> 6][2] = s3; }
  __syncthreads();
  if (t == 0) {
    float r1 = 0.f, r2 = 0.f, r3 = 0.f;
#pragma unroll
    for (int w = 0; w < 8; ++w) { r1 += pr[w][0]; r2 += pr[w][1]; r3 += pr[w][2]; }
    pp[0 * B_ * 64 + b * 64 + chunk] = r1;
    pp[1 * B_ * 64 + b * 64 + chunk] = r2;
    pp[2 * B_ * 64 + b * 64 + chunk] = r3;
  }
}

// ---------------------------------------------------------------------------
// K2: moment aggregation + analytic epilogue.
// VE_p[f] = sum_n e^p * v[b][f][n], p = 0..3.  out = A + k*(q*A - B), with
// A, B, q computed from the moments in double precision (series in alpha,
// truncation error ~1e-13 relative).
// 1024 blocks (b = bid&7 for XCD/L2 affinity on e[b]; 128 f-groups x 2 f),
// 256 threads, 4 blocks/CU.
// ---------------------------------------------------------------------------
__global__ __launch_bounds__(256, 4) void agg_kernel(
    const float* __restrict__ e, const float* __restrict__ values,
    const float* __restrict__ pp, float* __restrict__ out) {
  const int b = blockIdx.x & 7;
  const int f0 = (blockIdx.x >> 3) * 2;
  const int t = threadIdx.x;
  const float* eb = e + (size_t)b * N_;
  const float* vp0 = values + ((size_t)b * F_ + f0) * N_;
  const float* vp1 = vp0 + N_;

  float4 a0[2], a1[2], a2[2], a3[2];
#pragma unroll
  for (int f = 0; f < 2; ++f) {
    a0[f] = make_float4(0, 0, 0, 0); a1[f] = make_float4(0, 0, 0, 0);
    a2[f] = make_float4(0, 0, 0, 0); a3[f] = make_float4(0, 0, 0, 0);
  }

#pragma unroll 2
  for (int it = 0; it < 32; ++it) {
    const int n0 = (it * 256 + t) * 4;
    float4 e1 = *reinterpret_cast<const float4*>(eb + n0);
    float4 e2 = make_float4(e1.x * e1.x, e1.y * e1.y, e1.z * e1.z, e1.w * e1.w);
    float4 e3 = make_float4(e2.x * e1.x, e2.y * e1.y, e2.z * e1.z, e2.w * e1.w);
    float4 va = *reinterpret_cast<const float4*>(vp0 + n0);
    a0[0].x += va.x;        a0[0].y += va.y;        a0[0].z += va.z;        a0[0].w += va.w;
    a1[0].x += va.x * e1.x; a1[0].y += va.y * e1.y; a1[0].z += va.z * e1.z; a1[0].w += va.w * e1.w;
    a2[0].x += va.x * e2.x; a2[0].y += va.y * e2.y; a2[0].z += va.z * e2.z; a2[0].w += va.w * e2.w;
    a3[0].x += va.x * e3.x; a3[0].y += va.y * e3.y; a3[0].z += va.z * e3.z; a3[0].w += va.w * e3.w;
    float4 vb = *reinterpret_cast<const float4*>(vp1 + n0);
    a0[1].x += vb.x;        a0[1].y += vb.y;        a0[1].z += vb.z;        a0[1].w += vb.w;
    a1[1].x += vb.x * e1.x; a1[1].y += vb.y * e1.y; a1[1].z += vb.z * e1.z; a1[1].w += vb.w * e1.w;
    a2[1].x += vb.x * e2.x; a2[1].y += vb.y * e2.y; a2[1].z += vb.z * e2.z; a2[1].w += vb.w * e2.w;
    a3[1].x += vb.x * e3.x; a3[1].y += vb.y * e3.y; a3[1].z += vb.z * e3.z; a3[1].w += vb.w * e3.w;
  }

  // fold to 8 scalars: order [V0_f0, V0_f1, VE1_f0, VE1_f1, VE2_f0, VE2_f1, VE3_f0, VE3_f1]
  float S[8] = {sum4(a0[0]), sum4(a0[1]), sum4(a1[0]), sum4(a1[1]),
                sum4(a2[0]), sum4(a2[1]), sum4(a3[0]), sum4(a3[1])};
#pragma unroll
  for (int i = 0; i < 8; ++i) {
#pragma unroll
    for (int off = 32; off > 0; off >>= 1) S[i] += __shfl_xor(S[i], off, 64);
  }
  __shared__ float red[4][8];
  __shared__ double dsc[4];
  const int wid = t >> 6, lane = t & 63;
  if (lane == 0) {
#pragma unroll
    for (int i = 0; i < 8; ++i) red[wid][i] = S[i];
  }
  __syncthreads();

  // wave 0: scalar sums in double + analytic epilogue
  if (t < 64) {
    double z1 = (double)pp[b * 64 + t];
    double w2 = (double)pp[B_ * 64 + b * 64 + t];
    double w3 = (double)pp[2 * B_ * 64 + b * 64 + t];
#pragma unroll
    for (int off = 32; off > 0; off >>= 1) {
      z1 += __shfl_xor(z1, off, 64);
      w2 += __shfl_xor(w2, off, 64);
      w3 += __shfl_xor(w3, off, 64);
    }
    if (t == 0) {
      double V[8];
#pragma unroll
      for (int i = 0; i < 8; ++i)
        V[i] = (double)red[0][i] + (double)red[1][i] + (double)red[2][i] + (double)red[3][i];
      const double iZ1 = 1.0 / z1;
      const double M2 = w2 * iZ1 * iZ1;
      const double M3 = w3 * iZ1 * iZ1 * iZ1;
      const double Z2 = (double)N_ + 1.0 + 0.5 * M2 + M3 / 6.0;
      const double T2 = (double)N_ + 2.0 + 2.0 * M2 + (4.0 / 3.0) * M3;
      const double iZ2 = 1.0 / Z2;
      const double qd = T2 * iZ2 * iZ2;
#pragma unroll
      for (int f = 0; f < 2; ++f) {
        const double W0 = V[f];
        const double W1 = V[2 + f] * iZ1;
        const double W2 = V[4 + f] * iZ1 * iZ1;
        const double W3 = V[6 + f] * iZ1 * iZ1 * iZ1;
        const double A  = (W0 + W1 + 0.5 * W2 + W3 / 6.0) * iZ2;
        const double Bd = (W0 + 2.0 * W1 + 2.0 * W2 + (4.0 / 3.0) * W3) * iZ2 * iZ2;
        dsc[f * 2]     = A;
        dsc[f * 2 + 1] = qd * A - Bd;
      }
    }
  }
  __syncthreads();
  if (t < 32) {
    const int k = t & 15, f = t >> 4;
    const double A = dsc[f * 2], C = dsc[f * 2 + 1];
    out[((size_t)b * K_ + k) * F_ + f0 + f] = (float)(A + (double)k * C);
  }
}

extern "C" void kernel_launch(void* const* d_in, const int* in_sizes, int n_in,
                              void* d_out, int out_size, void* d_ws, size_t ws_size,
                              hipStream_t stream) {
  const float* q = (const float*)d_in[0];
  const float* keys = (const float*)d_in[1];
  const float* values = (const float*)d_in[2];
  float* out = (float*)d_out;
  float* ws = (float*)d_ws;
  float* e = ws;                              // B*N floats = 1 MB
  float* pp = ws + (size_t)B_ * N_;           // 3*B*64 floats

  expsim_kernel<<<dim3(512), dim3(512), 0, stream>>>(q, keys, e, pp);
  agg_kernel<<<dim3(1024), dim3(256), 0, stream>>>(e, values, pp, out);
}